// Round 2
// baseline (198.685 us; speedup 1.0000x reference)
//
#include <hip/hip_runtime.h>
#include <stdint.h>

#define N_NODES 8192
#define KPAD 272
#define OUTC 384

typedef __attribute__((ext_vector_type(8))) short bhalf8;
typedef __attribute__((ext_vector_type(16))) float f32x16;
typedef __attribute__((ext_vector_type(4))) float f32x4;

__device__ inline unsigned short f2bf_rne(float f) {
    unsigned u = __builtin_bit_cast(unsigned, f);
    u += 0x7FFFu + ((u >> 16) & 1u);
    return (unsigned short)(u >> 16);
}

__device__ inline bhalf8 mk8(unsigned a, unsigned b, unsigned c, unsigned d) {
    union { unsigned u[4]; bhalf8 v; } U;
    U.u[0] = a; U.u[1] = b; U.u[2] = c; U.u[3] = d;
    return U.v;
}

#define GLD_TO_LDS(gptr, lptr)                                                              \
    __builtin_amdgcn_global_load_lds((const __attribute__((address_space(1))) void*)(gptr), \
                                     (__attribute__((address_space(3))) void*)(lptr), 16, 0, 0)

// ---------------- prep (weights only): WcatT, WrT, bcat ----------------
__global__ void k_prep(const float* __restrict__ Wi, const float* __restrict__ bi,
                       const float* __restrict__ Wj, const float* __restrict__ bj,
                       const float* __restrict__ Wk, const float* __restrict__ bk,
                       const float* __restrict__ Wr,
                       unsigned short* __restrict__ WcatT, unsigned short* __restrict__ WrT,
                       float* __restrict__ bcat) {
    int idx = blockIdx.x * 256 + threadIdx.x;
    const int WC_N = OUTC * KPAD;      // 104,448
    const int WR_N = 256 * 128;        // 32,768
    if (idx < WC_N) {
        int n = idx / KPAD, kk = idx - n * KPAD;
        int sel = n >> 7, d = n & 127;
        const float* W = (sel == 0) ? Wi : ((sel == 1) ? Wj : Wk);
        float v = 0.f;
        if (kk < 256) v = W[(kk + 3) * 128 + d];
        else if (kk < 259) v = W[(kk - 256) * 128 + d];
        WcatT[idx] = f2bf_rne(v);
        return;
    }
    idx -= WC_N;
    if (idx < WR_N) {
        int c = idx >> 7, d = idx & 127;
        WrT[idx] = f2bf_rne(Wr[d * 256 + c]);
        return;
    }
    idx -= WR_N;
    if (idx < OUTC) {
        float v = (idx < 128) ? bi[idx] : ((idx < 256) ? bj[idx - 128] : bk[idx - 256]);
        bcat[idx] = v;
    }
}

// ---------------- k1: projections straight from f32 inputs -> fi, fj, fkT ----------------
// grid = 256 i-tiles x 3 n-groups (ng 0=fi, 1=fj, 2=fkT); A-fragments built in regs.
__global__ __launch_bounds__(256) void k_proj(const float* __restrict__ landmarks,
                                              const float* __restrict__ features,
                                              const unsigned short* __restrict__ WcatT,
                                              const float* __restrict__ bcat,
                                              unsigned short* __restrict__ fi,
                                              unsigned short* __restrict__ fj,
                                              unsigned short* __restrict__ fkT) {
    const int tid = threadIdx.x, w = tid >> 6, l = tid & 63, h = l >> 5, ln = l & 31;
    const unsigned bid = blockIdx.x;
    const int it = bid / 3, ng = bid - it * 3;
    const int i0 = it * 32;
    const int n = ng * 128 + w * 32 + ln;
    const int row = i0 + ln;
    f32x16 acc = {};
#pragma unroll
    for (int s = 0; s < 17; ++s) {
        union { unsigned short us[8]; bhalf8 v; } A;
        if (s < 16) {
            const float* fp = features + (size_t)row * 256 + s * 16 + h * 8;
            f32x4 v0 = *(const f32x4*)(fp);
            f32x4 v1 = *(const f32x4*)(fp + 4);
#pragma unroll
            for (int e = 0; e < 4; ++e) { A.us[e] = f2bf_rne(v0[e]); A.us[4 + e] = f2bf_rne(v1[e]); }
        } else {
#pragma unroll
            for (int e = 0; e < 8; ++e) A.us[e] = 0;
            if (h == 0) {
                A.us[0] = f2bf_rne(landmarks[row * 3 + 0]);
                A.us[1] = f2bf_rne(landmarks[row * 3 + 1]);
                A.us[2] = f2bf_rne(landmarks[row * 3 + 2]);
            }
        }
        bhalf8 b = *(const bhalf8*)(WcatT + (size_t)n * KPAD + s * 16 + h * 8);
        acc = __builtin_amdgcn_mfma_f32_32x32x16_bf16(A.v, b, acc, 0, 0, 0);
    }
    const int d = w * 32 + ln;
    const float bias = bcat[n];
    if (ng < 2) {
        unsigned short* dst = ng ? fj : fi;
#pragma unroll
        for (int q = 0; q < 4; ++q) {
            int ib = i0 + 8 * q + 4 * h;
#pragma unroll
            for (int r = 0; r < 4; ++r)
                dst[(size_t)(ib + r) * 128 + d] = f2bf_rne(acc[4 * q + r] + bias);
        }
    } else {
#pragma unroll
        for (int q = 0; q < 4; ++q) {
            int ib = i0 + 8 * q + 4 * h;
            ushort4 pk;
            pk.x = f2bf_rne(acc[4 * q + 0] + bias);
            pk.y = f2bf_rne(acc[4 * q + 1] + bias);
            pk.z = f2bf_rne(acc[4 * q + 2] + bias);
            pk.w = f2bf_rne(acc[4 * q + 3] + bias);
            *(ushort4*)(fkT + (size_t)d * N_NODES + ib) = pk;
        }
    }
}

// ---------------- k2: fused sigmoid-attention, 128-i blocks, double-buffered 64-j chunks ----
// Wave w: ih = w>>1 (64-i half, 2 nt subtiles), jh = w&1 (32-j half of the chunk).
// fj tile: [64 j][256 B] chunks swizzled ^(r&15).  fk tile: paired rows [64 r][256 B] where
// row r holds d=r (chunks 0-7) and d=r+64 (chunks 8-15), slot = g ^ (r&15) -> 2-way, free.
__global__ __launch_bounds__(256, 2) void k_attn(const unsigned short* __restrict__ fi,
                                                 const unsigned short* __restrict__ fj,
                                                 const unsigned short* __restrict__ fkT,
                                                 float* __restrict__ num_part,
                                                 float* __restrict__ den_part) {
    __shared__ __align__(16) char smem[65536];
    char* const fjb0 = smem;             // 16 KB
    char* const fkb0 = smem + 16384;     // 16 KB
    char* const fjb1 = smem + 32768;
    char* const fkb1 = smem + 49152;

    const int tid = threadIdx.x;
    const int w = tid >> 6, l = tid & 63, h = l >> 5, ln = l & 31;
    const int ih = w >> 1, jh = w & 1;
    const int rt = blockIdx.x & 63, jq = blockIdx.x >> 6;   // 512 blocks = 64 rt x 8 jq
    const int i0 = rt * 128;
    const int jbase = jq * 1024;

    const int rsub = l >> 4, cph = l & 15;

    // hoist fi B-fragments for this wave's 64-i half (64 VGPRs)
    bhalf8 bfi[2][8];
#pragma unroll
    for (int nt = 0; nt < 2; ++nt)
#pragma unroll
        for (int s = 0; s < 8; ++s)
            bfi[nt][s] = *(const bhalf8*)(fi + (size_t)(i0 + ih * 64 + nt * 32 + ln) * 128 + s * 16 + h * 8);

    f32x16 acc[8] = {};   // [m4 0..3][nt 0..1] -> numT[d 128][i 64-half]
    float dacc0 = 0.f, dacc1 = 0.f;

    auto STAGE = [&](char* fjd, char* fkd, int J0) {
#pragma unroll
        for (int q = 0; q < 4; ++q) {
            int r = w * 16 + q * 4 + rsub;
            int c = cph ^ (r & 15);
            GLD_TO_LDS(fj + (size_t)(J0 + r) * 128 + c * 8, fjd + (w * 16 + q * 4) * 256);
        }
#pragma unroll
        for (int q = 0; q < 4; ++q) {
            int r = w * 16 + q * 4 + rsub;
            int g = cph ^ (r & 15);
            int d = r + ((g >> 3) << 6);
            int joff = (g & 7) * 8;
            GLD_TO_LDS(fkT + (size_t)d * N_NODES + J0 + joff, fkd + (w * 16 + q * 4) * 256);
        }
    };

    auto COMPUTE = [&](const char* fjbuf, const char* fkbuf) {
        // S^T: [wave's 32 j] x [64 i]
        f32x16 st0 = {}, st1 = {};
        const int jrow = jh * 32 + ln;
        __builtin_amdgcn_s_setprio(1);
#pragma unroll
        for (int s = 0; s < 8; ++s) {
            int c = (s * 2 + h) ^ (jrow & 15);
            bhalf8 af = *(const bhalf8*)(fjbuf + jrow * 256 + c * 16);
            st0 = __builtin_amdgcn_mfma_f32_32x32x16_bf16(af, bfi[0][s], st0, 0, 0, 0);
            st1 = __builtin_amdgcn_mfma_f32_32x32x16_bf16(af, bfi[1][s], st1, 0, 0, 0);
        }
        __builtin_amdgcn_s_setprio(0);
        // sigmoid + denom + pack consecutive-j pairs to bf16
        float sv0[16], sv1[16];
#pragma unroll
        for (int r = 0; r < 16; ++r) {
            float x0 = __builtin_amdgcn_rcpf(1.f + __builtin_amdgcn_exp2f(st0[r] * -1.44269504f));
            float x1 = __builtin_amdgcn_rcpf(1.f + __builtin_amdgcn_exp2f(st1[r] * -1.44269504f));
            dacc0 += x0; dacc1 += x1;
            sv0[r] = x0; sv1[r] = x1;
        }
        unsigned p0[8], p1[8], x0v[8], x1v[8];
#pragma unroll
        for (int q = 0; q < 8; ++q) {
            p0[q] = __builtin_amdgcn_perm(__builtin_bit_cast(unsigned, sv0[2 * q + 1]),
                                          __builtin_bit_cast(unsigned, sv0[2 * q]), 0x07060302u);
            p1[q] = __builtin_amdgcn_perm(__builtin_bit_cast(unsigned, sv1[2 * q + 1]),
                                          __builtin_bit_cast(unsigned, sv1[2 * q]), 0x07060302u);
        }
#pragma unroll
        for (int q = 0; q < 8; ++q) {
            x0v[q] = (unsigned)__shfl_xor((int)p0[q], 32, 64);
            x1v[q] = (unsigned)__shfl_xor((int)p1[q], 32, 64);
        }
        bhalf8 fb[2][2];
        if (h == 0) {
            fb[0][0] = mk8(p0[0], p0[1], x0v[0], x0v[1]);
            fb[0][1] = mk8(p0[4], p0[5], x0v[4], x0v[5]);
            fb[1][0] = mk8(p1[0], p1[1], x1v[0], x1v[1]);
            fb[1][1] = mk8(p1[4], p1[5], x1v[4], x1v[5]);
        } else {
            fb[0][0] = mk8(x0v[2], x0v[3], p0[2], p0[3]);
            fb[0][1] = mk8(x0v[6], x0v[7], p0[6], p0[7]);
            fb[1][0] = mk8(x1v[2], x1v[3], p1[2], p1[3]);
            fb[1][1] = mk8(x1v[6], x1v[7], p1[6], p1[7]);
        }
        // PV: numT[d][i] += fk[d][j-slice] * P^T[j-slice][i]
        __builtin_amdgcn_s_setprio(1);
#pragma unroll
        for (int m4 = 0; m4 < 4; ++m4) {
            int d = m4 * 32 + ln;
            int r = d & 63;
            int ghi = (d >> 6) << 3;
#pragma unroll
            for (int s2 = 0; s2 < 2; ++s2) {
                int g = ghi | (jh * 4 + s2 * 2 + h);
                int slot = g ^ (r & 15);
                bhalf8 af = *(const bhalf8*)(fkbuf + r * 256 + slot * 16);
                acc[m4 * 2 + 0] = __builtin_amdgcn_mfma_f32_32x32x16_bf16(af, fb[0][s2], acc[m4 * 2 + 0], 0, 0, 0);
                acc[m4 * 2 + 1] = __builtin_amdgcn_mfma_f32_32x32x16_bf16(af, fb[1][s2], acc[m4 * 2 + 1], 0, 0, 0);
            }
        }
        __builtin_amdgcn_s_setprio(0);
    };

    STAGE(fjb0, fkb0, jbase);
    __syncthreads();
#pragma unroll 1
    for (int mt = 0; mt < 16; mt += 2) {
        STAGE(fjb1, fkb1, jbase + (mt + 1) * 64);
        COMPUTE(fjb0, fkb0);
        __syncthreads();
        if (mt + 2 < 16) STAGE(fjb0, fkb0, jbase + (mt + 2) * 64);
        COMPUTE(fjb1, fkb1);
        __syncthreads();
    }

    // denom: fold h halves, stash [jh][128 i]
    dacc0 += __shfl_xor(dacc0, 32, 64);
    dacc1 += __shfl_xor(dacc1, 32, 64);
    float* denb = (float*)(smem + 34816);   // 256 f32, right after the 34,816 B reduce buf
    if (h == 0) {
        denb[jh * 128 + ih * 64 + ln] = dacc0;
        denb[jh * 128 + ih * 64 + 32 + ln] = dacc1;
    }

    // num reduce over jh in two 64-d halves; buf [128 i][68] f32
    float* buf = (float*)smem;
#pragma unroll
    for (int half = 0; half < 2; ++half) {
        __syncthreads();
        if (jh == 0) {
#pragma unroll
            for (int m2 = 0; m2 < 2; ++m2) {
                int m4 = half * 2 + m2;
#pragma unroll
                for (int nt = 0; nt < 2; ++nt) {
                    int irow = ih * 64 + nt * 32 + ln;
#pragma unroll
                    for (int q = 0; q < 4; ++q) {
                        int dd = m2 * 32 + 8 * q + 4 * h;
                        f32x4 v = {acc[m4 * 2 + nt][4 * q + 0], acc[m4 * 2 + nt][4 * q + 1],
                                   acc[m4 * 2 + nt][4 * q + 2], acc[m4 * 2 + nt][4 * q + 3]};
                        *(f32x4*)(buf + irow * 68 + dd) = v;
                    }
                }
            }
        }
        __syncthreads();
        if (jh == 1) {
#pragma unroll
            for (int m2 = 0; m2 < 2; ++m2) {
                int m4 = half * 2 + m2;
#pragma unroll
                for (int nt = 0; nt < 2; ++nt) {
                    int irow = ih * 64 + nt * 32 + ln;
#pragma unroll
                    for (int q = 0; q < 4; ++q) {
                        int dd = m2 * 32 + 8 * q + 4 * h;
                        float* p4 = buf + irow * 68 + dd;
                        f32x4 old = *(f32x4*)p4;
                        f32x4 v = {acc[m4 * 2 + nt][4 * q + 0], acc[m4 * 2 + nt][4 * q + 1],
                                   acc[m4 * 2 + nt][4 * q + 2], acc[m4 * 2 + nt][4 * q + 3]};
                        *(f32x4*)p4 = old + v;
                    }
                }
            }
        }
        __syncthreads();
#pragma unroll
        for (int e = 0; e < 8; ++e) {
            int v = e * 256 + tid;             // 2048 float4s = 128 i x 16
            int iloc = v >> 4, dq = v & 15;
            *(f32x4*)(num_part + ((size_t)(jq * N_NODES + i0 + iloc)) * 128 + half * 64 + dq * 4) =
                *(const f32x4*)(buf + iloc * 68 + dq * 4);
        }
    }
    __syncthreads();
    if (tid < 128) {
        den_part[(size_t)jq * N_NODES + i0 + tid] = denb[tid] + denb[128 + tid];
    }
}

// ---------------- k3: t = (sum num)/(sum den); out = t @ Wr + br + features ----------------
__global__ __launch_bounds__(256) void k_out(const unsigned short* __restrict__ WrT,
                                             const float* __restrict__ br,
                                             const float* __restrict__ features,
                                             const float* __restrict__ num_part,
                                             const float* __restrict__ den_part,
                                             float* __restrict__ out) {
    __shared__ __align__(16) char smem[73728];
    char* const tb = smem + 65536;   // t tile [32 i][256 B] swizzled, 8 KB
    const int tid = threadIdx.x, w = tid >> 6, l = tid & 63, h = l >> 5, ln = l & 31;
    const int i0 = blockIdx.x * 32;
    // stage WrT (64 KB) async into smem[0..64K)
    {
        int rsub = l >> 4, cph = l & 15;
#pragma unroll
        for (int q = 0; q < 16; ++q) {
            int r = w * 64 + q * 4 + rsub;
            int c = cph ^ (r & 15);
            GLD_TO_LDS(WrT + (size_t)r * 128 + c * 8, smem + (w * 64 + q * 4) * 256);
        }
    }
    // combine num/den partials -> t tile (bf16) while staging lands
    {
        int i = tid >> 3, dseg = (tid & 7) * 16;
        f32x4 s[4] = {};
        float ds = 0.f;
#pragma unroll
        for (int q = 0; q < 8; ++q) {
            const float* np = num_part + ((size_t)(q * N_NODES + i0 + i)) * 128 + dseg;
#pragma unroll
            for (int k = 0; k < 4; ++k) s[k] += *(const f32x4*)(np + 4 * k);
            ds += den_part[(size_t)q * N_NODES + i0 + i];
        }
        float inv = 1.0f / ds;
#pragma unroll
        for (int cc = 0; cc < 2; ++cc) {
            union { unsigned u[4]; bhalf8 v; } U;
#pragma unroll
            for (int m = 0; m < 4; ++m) {
                int e0 = cc * 8 + 2 * m;
                unsigned lo = f2bf_rne(s[e0 >> 2][e0 & 3] * inv);
                unsigned hi = f2bf_rne(s[(e0 + 1) >> 2][(e0 + 1) & 3] * inv);
                U.u[m] = lo | (hi << 16);
            }
            int slot = ((tid & 7) * 2 + cc) ^ (i & 15);
            *(bhalf8*)(tb + i * 256 + slot * 16) = U.v;
        }
    }
    __syncthreads();
    f32x16 acc[2] = {};
#pragma unroll
    for (int s = 0; s < 8; ++s) {
        int ca = (s * 2 + h) ^ (ln & 15);
        bhalf8 af = *(const bhalf8*)(tb + ln * 256 + ca * 16);
#pragma unroll
        for (int nt = 0; nt < 2; ++nt) {
            int row = w * 64 + nt * 32 + ln;
            int c = (s * 2 + h) ^ (row & 15);
            bhalf8 bf = *(const bhalf8*)(smem + row * 256 + c * 16);
            acc[nt] = __builtin_amdgcn_mfma_f32_32x32x16_bf16(af, bf, acc[nt], 0, 0, 0);
        }
    }
#pragma unroll
    for (int nt = 0; nt < 2; ++nt) {
        int cc = w * 64 + nt * 32 + ln;
        float bias = br[cc];
#pragma unroll
        for (int q = 0; q < 4; ++q) {
#pragma unroll
            for (int r = 0; r < 4; ++r) {
                int i = i0 + 8 * q + 4 * h + r;
                out[(size_t)i * 256 + cc] = acc[nt][4 * q + r] + bias + features[(size_t)i * 256 + cc];
            }
        }
    }
}

extern "C" void kernel_launch(void* const* d_in, const int* in_sizes, int n_in,
                              void* d_out, int out_size, void* d_ws, size_t ws_size,
                              hipStream_t stream) {
    const float* landmarks = (const float*)d_in[0];
    const float* features  = (const float*)d_in[1];
    const float* Wi = (const float*)d_in[2];
    const float* bi = (const float*)d_in[3];
    const float* Wj = (const float*)d_in[4];
    const float* bj = (const float*)d_in[5];
    const float* Wk = (const float*)d_in[6];
    const float* bk = (const float*)d_in[7];
    const float* Wr = (const float*)d_in[8];
    const float* br = (const float*)d_in[9];

    char* ws = (char*)d_ws;
    unsigned short* WcatT   = (unsigned short*)(ws + 0);         // 384x272 bf16   (208,896 B)
    unsigned short* WrT     = (unsigned short*)(ws + 208896);    // 256x128 bf16   (65,536 B)
    float*          bcat    = (float*)(ws + 274432);             // 384 f32        (1,536 B)
    unsigned short* fi      = (unsigned short*)(ws + 275968);    // 8192x128 bf16  (2,097,152 B)
    unsigned short* fjp     = (unsigned short*)(ws + 2373120);   // 8192x128 bf16
    unsigned short* fkT     = (unsigned short*)(ws + 4470272);   // 128x8192 bf16
    float*          num_part= (float*)(ws + 6567424);            // 8x8192x128 f32 (33,554,432 B)
    float*          den_part= (float*)(ws + 40121856);           // 8x8192 f32     (262,144 B)

    float* out = (float*)d_out;

    hipLaunchKernelGGL(k_prep, dim3(538), dim3(256), 0, stream,
                       Wi, bi, Wj, bj, Wk, bk, Wr, WcatT, WrT, bcat);
    hipLaunchKernelGGL(k_proj, dim3(768), dim3(256), 0, stream,
                       landmarks, features, WcatT, bcat, fi, fjp, fkT);
    hipLaunchKernelGGL(k_attn, dim3(512), dim3(256), 0, stream, fi, fjp, fkT, num_part, den_part);
    hipLaunchKernelGGL(k_out, dim3(256), dim3(256), 0, stream,
                       WrT, br, features, num_part, den_part, out);
}

// Round 3
// 151.626 us; speedup vs baseline: 1.3104x; 1.3104x over previous
//
#include <hip/hip_runtime.h>
#include <stdint.h>

#define N_NODES 8192
#define KPAD 272
#define OUTC 384

typedef __attribute__((ext_vector_type(8))) short bhalf8;
typedef __attribute__((ext_vector_type(16))) float f32x16;
typedef __attribute__((ext_vector_type(4))) float f32x4;

__device__ inline unsigned short f2bf_rne(float f) {
    unsigned u = __builtin_bit_cast(unsigned, f);
    u += 0x7FFFu + ((u >> 16) & 1u);
    return (unsigned short)(u >> 16);
}

__device__ inline bhalf8 mk8(unsigned a, unsigned b, unsigned c, unsigned d) {
    union { unsigned u[4]; bhalf8 v; } U;
    U.u[0] = a; U.u[1] = b; U.u[2] = c; U.u[3] = d;
    return U.v;
}

#define GLD_TO_LDS(gptr, lptr)                                                              \
    __builtin_amdgcn_global_load_lds((const __attribute__((address_space(1))) void*)(gptr), \
                                     (__attribute__((address_space(3))) void*)(lptr), 16, 0, 0)

// ---------------- prep (weights only): WcatT, WrT, bcat ----------------
__global__ void k_prep(const float* __restrict__ Wi, const float* __restrict__ bi,
                       const float* __restrict__ Wj, const float* __restrict__ bj,
                       const float* __restrict__ Wk, const float* __restrict__ bk,
                       const float* __restrict__ Wr,
                       unsigned short* __restrict__ WcatT, unsigned short* __restrict__ WrT,
                       float* __restrict__ bcat) {
    int idx = blockIdx.x * 256 + threadIdx.x;
    const int WC_N = OUTC * KPAD;      // 104,448
    const int WR_N = 256 * 128;        // 32,768
    if (idx < WC_N) {
        int n = idx / KPAD, kk = idx - n * KPAD;
        int sel = n >> 7, d = n & 127;
        const float* W = (sel == 0) ? Wi : ((sel == 1) ? Wj : Wk);
        float v = 0.f;
        if (kk < 256) v = W[(kk + 3) * 128 + d];
        else if (kk < 259) v = W[(kk - 256) * 128 + d];
        WcatT[idx] = f2bf_rne(v);
        return;
    }
    idx -= WC_N;
    if (idx < WR_N) {
        int c = idx >> 7, d = idx & 127;
        WrT[idx] = f2bf_rne(Wr[d * 256 + c]);
        return;
    }
    idx -= WR_N;
    if (idx < OUTC) {
        float v = (idx < 128) ? bi[idx] : ((idx < 256) ? bj[idx - 128] : bk[idx - 256]);
        bcat[idx] = v;
    }
}

// ---------------- k1: projections straight from f32 inputs -> fi, fj, fkT ----------------
// grid = 256 i-tiles x 3 n-groups (ng 0=fi, 1=fj, 2=fkT); A-fragments built in regs.
__global__ __launch_bounds__(256) void k_proj(const float* __restrict__ landmarks,
                                              const float* __restrict__ features,
                                              const unsigned short* __restrict__ WcatT,
                                              const float* __restrict__ bcat,
                                              unsigned short* __restrict__ fi,
                                              unsigned short* __restrict__ fj,
                                              unsigned short* __restrict__ fkT) {
    const int tid = threadIdx.x, w = tid >> 6, l = tid & 63, h = l >> 5, ln = l & 31;
    const unsigned bid = blockIdx.x;
    const int it = bid / 3, ng = bid - it * 3;
    const int i0 = it * 32;
    const int n = ng * 128 + w * 32 + ln;
    const int row = i0 + ln;
    f32x16 acc = {};
#pragma unroll
    for (int s = 0; s < 17; ++s) {
        union { unsigned short us[8]; bhalf8 v; } A;
        if (s < 16) {
            const float* fp = features + (size_t)row * 256 + s * 16 + h * 8;
            f32x4 v0 = *(const f32x4*)(fp);
            f32x4 v1 = *(const f32x4*)(fp + 4);
#pragma unroll
            for (int e = 0; e < 4; ++e) { A.us[e] = f2bf_rne(v0[e]); A.us[4 + e] = f2bf_rne(v1[e]); }
        } else {
#pragma unroll
            for (int e = 0; e < 8; ++e) A.us[e] = 0;
            if (h == 0) {
                A.us[0] = f2bf_rne(landmarks[row * 3 + 0]);
                A.us[1] = f2bf_rne(landmarks[row * 3 + 1]);
                A.us[2] = f2bf_rne(landmarks[row * 3 + 2]);
            }
        }
        bhalf8 b = *(const bhalf8*)(WcatT + (size_t)n * KPAD + s * 16 + h * 8);
        acc = __builtin_amdgcn_mfma_f32_32x32x16_bf16(A.v, b, acc, 0, 0, 0);
    }
    const int d = w * 32 + ln;
    const float bias = bcat[n];
    if (ng < 2) {
        unsigned short* dst = ng ? fj : fi;
#pragma unroll
        for (int q = 0; q < 4; ++q) {
            int ib = i0 + 8 * q + 4 * h;
#pragma unroll
            for (int r = 0; r < 4; ++r)
                dst[(size_t)(ib + r) * 128 + d] = f2bf_rne(acc[4 * q + r] + bias);
        }
    } else {
#pragma unroll
        for (int q = 0; q < 4; ++q) {
            int ib = i0 + 8 * q + 4 * h;
            ushort4 pk;
            pk.x = f2bf_rne(acc[4 * q + 0] + bias);
            pk.y = f2bf_rne(acc[4 * q + 1] + bias);
            pk.z = f2bf_rne(acc[4 * q + 2] + bias);
            pk.w = f2bf_rne(acc[4 * q + 3] + bias);
            *(ushort4*)(fkT + (size_t)d * N_NODES + ib) = pk;
        }
    }
}

// ---------------- k2: fused sigmoid-attention, 64-i blocks, double-buffered 64-j chunks ----
// Wave w: ih = w>>1 (32-i half), jh = w&1 (32-j half of the chunk).
// fj tile: [64 j][256 B] chunks swizzled ^(r&15).
// fk tile: paired rows [64 r][256 B] where row r holds d=r (chunks g 0-7, j-offset (g&7)*8)
// and d=r+64 (chunks g 8-15); slot = g ^ (r&15) -> 2-way access, conflict-free.
__global__ __launch_bounds__(256, 2) void k_attn(const unsigned short* __restrict__ fi,
                                                 const unsigned short* __restrict__ fj,
                                                 const unsigned short* __restrict__ fkT,
                                                 float* __restrict__ num_part,
                                                 float* __restrict__ den_part) {
    __shared__ __align__(16) char smem[65536];
    char* const fjb0 = smem;             // 16 KB
    char* const fkb0 = smem + 16384;     // 16 KB
    char* const fjb1 = smem + 32768;
    char* const fkb1 = smem + 49152;

    const int tid = threadIdx.x;
    const int w = tid >> 6, l = tid & 63, h = l >> 5, ln = l & 31;
    const int ih = w >> 1, jh = w & 1;
    const int rt = blockIdx.x & 127, jq = blockIdx.x >> 7;   // 512 blocks = 128 rt x 4 jq
    const int i0 = rt * 64;
    const int jbase = jq * 2048;

    const int rsub = l >> 4, cph = l & 15;

    // hoist fi B-fragments for this wave's 32-i block (32 VGPRs), reused across all j
    bhalf8 bfi[8];
#pragma unroll
    for (int s = 0; s < 8; ++s)
        bfi[s] = *(const bhalf8*)(fi + (size_t)(i0 + ih * 32 + ln) * 128 + s * 16 + h * 8);

    f32x16 acc[4] = {};   // numT partials: [d-tile 0..3][wave's 32 i], over wave's jh half
    float dacc = 0.f;

    auto STAGE = [&](char* fjd, char* fkd, int J0) {
#pragma unroll
        for (int q = 0; q < 4; ++q) {
            int r = w * 16 + q * 4 + rsub;
            int c = cph ^ (r & 15);
            GLD_TO_LDS(fj + (size_t)(J0 + r) * 128 + c * 8, fjd + (w * 16 + q * 4) * 256);
        }
#pragma unroll
        for (int q = 0; q < 4; ++q) {
            int r = w * 16 + q * 4 + rsub;
            int g = cph ^ (r & 15);
            int d = r + ((g >> 3) << 6);
            int joff = (g & 7) * 8;
            GLD_TO_LDS(fkT + (size_t)d * N_NODES + J0 + joff, fkd + (w * 16 + q * 4) * 256);
        }
    };

    auto COMPUTE = [&](const char* fjbuf, const char* fkbuf) {
        // S^T quadrant = fj[jh half] @ fi[ih half]^T
        f32x16 st = {};
        const int jrow = jh * 32 + ln;
        __builtin_amdgcn_s_setprio(1);
#pragma unroll
        for (int s = 0; s < 8; ++s) {
            int c = (s * 2 + h) ^ (jrow & 15);
            bhalf8 af = *(const bhalf8*)(fjbuf + jrow * 256 + c * 16);
            st = __builtin_amdgcn_mfma_f32_32x32x16_bf16(af, bfi[s], st, 0, 0, 0);
        }
        __builtin_amdgcn_s_setprio(0);
        // sigmoid + denom accumulate + pack consecutive-j pairs to bf16
        unsigned p[8], xw[8];
#pragma unroll
        for (int q = 0; q < 8; ++q) {
            float x0 = __builtin_amdgcn_rcpf(1.f + __builtin_amdgcn_exp2f(st[2 * q] * -1.44269504f));
            float x1 = __builtin_amdgcn_rcpf(1.f + __builtin_amdgcn_exp2f(st[2 * q + 1] * -1.44269504f));
            dacc += x0;
            dacc += x1;
            p[q] = __builtin_amdgcn_perm(__builtin_bit_cast(unsigned, x1),
                                         __builtin_bit_cast(unsigned, x0), 0x07060302u);
        }
#pragma unroll
        for (int q = 0; q < 8; ++q) xw[q] = (unsigned)__shfl_xor((int)p[q], 32, 64);
        // assemble P^T B-operand fragments (k = j_local within the wave's 32-j slice)
        bhalf8 fb[2];
        if (h == 0) {
            fb[0] = mk8(p[0], p[1], xw[0], xw[1]);
            fb[1] = mk8(p[4], p[5], xw[4], xw[5]);
        } else {
            fb[0] = mk8(xw[2], xw[3], p[2], p[3]);
            fb[1] = mk8(xw[6], xw[7], p[6], p[7]);
        }
        // PV: numT[d][i] += fk[d][j-slice] * P^T[j-slice][i]
        __builtin_amdgcn_s_setprio(1);
#pragma unroll
        for (int m4 = 0; m4 < 4; ++m4) {
            int d = m4 * 32 + ln;
            int r = d & 63;
            int ghi = (d >> 6) << 3;
#pragma unroll
            for (int s2 = 0; s2 < 2; ++s2) {
                int g = ghi | (jh * 4 + s2 * 2 + h);
                int slot = g ^ (r & 15);
                bhalf8 af = *(const bhalf8*)(fkbuf + r * 256 + slot * 16);
                acc[m4] = __builtin_amdgcn_mfma_f32_32x32x16_bf16(af, fb[s2], acc[m4], 0, 0, 0);
            }
        }
        __builtin_amdgcn_s_setprio(0);
    };

    // 2-phase pipeline: stage next chunk before computing current; single vmcnt-drain
    // barrier per chunk, placed AFTER compute so load latency hides under MFMA+sigmoid.
    STAGE(fjb0, fkb0, jbase);
    __syncthreads();
#pragma unroll 1
    for (int mt = 0; mt < 32; mt += 2) {
        STAGE(fjb1, fkb1, jbase + (mt + 1) * 64);
        COMPUTE(fjb0, fkb0);
        __syncthreads();
        if (mt + 2 < 32) STAGE(fjb0, fkb0, jbase + (mt + 2) * 64);
        COMPUTE(fjb1, fkb1);
        __syncthreads();
    }

    // denom: fold lane l <-> l^32 (h halves), stash per wave
    dacc += __shfl_xor(dacc, 32, 64);
    float* denb = (float*)(smem + 40960);   // 128 floats, disjoint from reduce buf
    if (h == 0) denb[w * 32 + ln] = dacc;

    // num reduce: jh=0 waves write [64 i][128 d] (pad 132), jh=1 waves add
    float* buf = (float*)smem;
    if (jh == 0) {
#pragma unroll
        for (int m4 = 0; m4 < 4; ++m4)
#pragma unroll
            for (int q = 0; q < 4; ++q) {
                f32x4 v = {acc[m4][4 * q + 0], acc[m4][4 * q + 1],
                           acc[m4][4 * q + 2], acc[m4][4 * q + 3]};
                *(f32x4*)(buf + (ih * 32 + ln) * 132 + m4 * 32 + 8 * q + 4 * h) = v;
            }
    }
    __syncthreads();
    if (jh == 1) {
#pragma unroll
        for (int m4 = 0; m4 < 4; ++m4)
#pragma unroll
            for (int q = 0; q < 4; ++q) {
                float* p4 = buf + (ih * 32 + ln) * 132 + m4 * 32 + 8 * q + 4 * h;
                f32x4 old = *(f32x4*)p4;
                f32x4 v = {acc[m4][4 * q + 0], acc[m4][4 * q + 1],
                           acc[m4][4 * q + 2], acc[m4][4 * q + 3]};
                *(f32x4*)p4 = old + v;
            }
    }
    __syncthreads();
#pragma unroll
    for (int e = 0; e < 8; ++e) {
        int v = e * 256 + tid;                 // 2048 float4s = 64 i x 32
        int iloc = v >> 5, d4 = (v & 31) * 4;
        *(f32x4*)(num_part + ((size_t)jq * N_NODES + i0 + iloc) * 128 + d4) =
            *(const f32x4*)(buf + iloc * 132 + d4);
    }
    if (tid < 64) {
        den_part[(size_t)jq * N_NODES + i0 + tid] =
            denb[(tid >> 5) * 64 + (tid & 31)] + denb[(tid >> 5) * 64 + 32 + (tid & 31)];
    }
}

// ---------------- k3: t = (sum num)/(sum den); out = t @ Wr + br + features ----------------
__global__ __launch_bounds__(256) void k_out(const unsigned short* __restrict__ WrT,
                                             const float* __restrict__ br,
                                             const float* __restrict__ features,
                                             const float* __restrict__ num_part,
                                             const float* __restrict__ den_part,
                                             float* __restrict__ out) {
    __shared__ __align__(16) char smem[73728];
    char* const tb = smem + 65536;   // t tile [32 i][256 B] swizzled, 8 KB
    const int tid = threadIdx.x, w = tid >> 6, l = tid & 63, h = l >> 5, ln = l & 31;
    const int i0 = blockIdx.x * 32;
    // stage WrT (64 KB) async into smem[0..64K)
    {
        int rsub = l >> 4, cph = l & 15;
#pragma unroll
        for (int q = 0; q < 16; ++q) {
            int r = w * 64 + q * 4 + rsub;
            int c = cph ^ (r & 15);
            GLD_TO_LDS(WrT + (size_t)r * 128 + c * 8, smem + (w * 64 + q * 4) * 256);
        }
    }
    // combine num/den partials -> t tile (bf16) while staging lands
    {
        int i = tid >> 3, dseg = (tid & 7) * 16;
        f32x4 s[4] = {};
        float ds = 0.f;
#pragma unroll
        for (int q = 0; q < 4; ++q) {
            const float* np = num_part + ((size_t)(q * N_NODES + i0 + i)) * 128 + dseg;
#pragma unroll
            for (int k = 0; k < 4; ++k) s[k] += *(const f32x4*)(np + 4 * k);
            ds += den_part[(size_t)q * N_NODES + i0 + i];
        }
        float inv = 1.0f / ds;
#pragma unroll
        for (int cc = 0; cc < 2; ++cc) {
            union { unsigned u[4]; bhalf8 v; } U;
#pragma unroll
            for (int m = 0; m < 4; ++m) {
                int e0 = cc * 8 + 2 * m;
                unsigned lo = f2bf_rne(s[e0 >> 2][e0 & 3] * inv);
                unsigned hi = f2bf_rne(s[(e0 + 1) >> 2][(e0 + 1) & 3] * inv);
                U.u[m] = lo | (hi << 16);
            }
            int slot = ((tid & 7) * 2 + cc) ^ (i & 15);
            *(bhalf8*)(tb + i * 256 + slot * 16) = U.v;
        }
    }
    __syncthreads();
    f32x16 acc[2] = {};
#pragma unroll
    for (int s = 0; s < 8; ++s) {
        int ca = (s * 2 + h) ^ (ln & 15);
        bhalf8 af = *(const bhalf8*)(tb + ln * 256 + ca * 16);
#pragma unroll
        for (int nt = 0; nt < 2; ++nt) {
            int row = w * 64 + nt * 32 + ln;
            int c = (s * 2 + h) ^ (row & 15);
            bhalf8 bf = *(const bhalf8*)(smem + row * 256 + c * 16);
            acc[nt] = __builtin_amdgcn_mfma_f32_32x32x16_bf16(af, bf, acc[nt], 0, 0, 0);
        }
    }
#pragma unroll
    for (int nt = 0; nt < 2; ++nt) {
        int cc = w * 64 + nt * 32 + ln;
        float bias = br[cc];
#pragma unroll
        for (int q = 0; q < 4; ++q) {
#pragma unroll
            for (int r = 0; r < 4; ++r) {
                int i = i0 + 8 * q + 4 * h + r;
                out[(size_t)i * 256 + cc] = acc[nt][4 * q + r] + bias + features[(size_t)i * 256 + cc];
            }
        }
    }
}

extern "C" void kernel_launch(void* const* d_in, const int* in_sizes, int n_in,
                              void* d_out, int out_size, void* d_ws, size_t ws_size,
                              hipStream_t stream) {
    const float* landmarks = (const float*)d_in[0];
    const float* features  = (const float*)d_in[1];
    const float* Wi = (const float*)d_in[2];
    const float* bi = (const float*)d_in[3];
    const float* Wj = (const float*)d_in[4];
    const float* bj = (const float*)d_in[5];
    const float* Wk = (const float*)d_in[6];
    const float* bk = (const float*)d_in[7];
    const float* Wr = (const float*)d_in[8];
    const float* br = (const float*)d_in[9];

    char* ws = (char*)d_ws;
    unsigned short* WcatT   = (unsigned short*)(ws + 0);         // 384x272 bf16   (208,896 B)
    unsigned short* WrT     = (unsigned short*)(ws + 208896);    // 256x128 bf16   (65,536 B)
    float*          bcat    = (float*)(ws + 274432);             // 384 f32        (1,536 B)
    unsigned short* fi      = (unsigned short*)(ws + 275968);    // 8192x128 bf16  (2,097,152 B)
    unsigned short* fjp     = (unsigned short*)(ws + 2373120);   // 8192x128 bf16
    unsigned short* fkT     = (unsigned short*)(ws + 4470272);   // 128x8192 bf16
    float*          num_part= (float*)(ws + 6567424);            // 4x8192x128 f32 (16,777,216 B)
    float*          den_part= (float*)(ws + 23344640);           // 4x8192 f32     (131,072 B)

    float* out = (float*)d_out;

    hipLaunchKernelGGL(k_prep, dim3(538), dim3(256), 0, stream,
                       Wi, bi, Wj, bj, Wk, bk, Wr, WcatT, WrT, bcat);
    hipLaunchKernelGGL(k_proj, dim3(768), dim3(256), 0, stream,
                       landmarks, features, WcatT, bcat, fi, fjp, fkT);
    hipLaunchKernelGGL(k_attn, dim3(512), dim3(256), 0, stream, fi, fjp, fkT, num_part, den_part);
    hipLaunchKernelGGL(k_out, dim3(256), dim3(256), 0, stream,
                       WrT, br, features, num_part, den_part, out);
}